// Round 4
// baseline (269.834 us; speedup 1.0000x reference)
//
#include <hip/hip_runtime.h>
#include <math.h>

#define THREADS 128   // block = 128 threads = 2 threads/token
#define TPB 64        // tokens per block
#define NEXP 256
#define EPS_S 2.0e-6f // single-score margins (score err <= ~4e-7, 2.5x safety)
#define EPS_G 4.0e-6f // group-sum margins

// ---- fast f32 sigmoid: hw v_exp_f32 + fast divide ----
__device__ __forceinline__ float fsigmoid(float x) {
    float e = __expf(-x);
    return __fdividef(1.0f, 1.0f + e);
}

// ---- cheap near-exact f64 sigmoid: Taylor exp + NR division (rare paths only) ----
__device__ __forceinline__ double dsigmoid(float xf) {
    xf = fminf(fmaxf(xf, -500.0f), 500.0f);
    double x = (double)xf;
    double t = x * -1.4426950408889634074;           // -x*log2(e)
    double n = floor(t + 0.5);
    int ni = (int)n;
    double u = (t - n) * 0.69314718055994530942;
    double pp = 2.08767569878680990e-9;
    pp = fma(pp, u, 2.50521083854417188e-8);
    pp = fma(pp, u, 2.75573192239858907e-7);
    pp = fma(pp, u, 2.75573192239858883e-6);
    pp = fma(pp, u, 2.48015873015873016e-5);
    pp = fma(pp, u, 1.98412698412698413e-4);
    pp = fma(pp, u, 1.38888888888888889e-3);
    pp = fma(pp, u, 8.33333333333333333e-3);
    pp = fma(pp, u, 4.16666666666666667e-2);
    pp = fma(pp, u, 1.66666666666666667e-1);
    pp = fma(pp, u, 0.5);
    pp = fma(pp, u, 1.0);
    pp = fma(pp, u, 1.0);
    double sc = __longlong_as_double((long long)(1023 + ni) << 52);
    double e = pp * sc;                              // exp(-x)
    double w = 1.0 + e;
    double y = (double)__fdividef(1.0f, (float)w);
    y = fma(y, fma(-w, y, 1.0), y);
    y = fma(y, fma(-w, y, 1.0), y);
    return y;
}

// per-group top-8 (val+id) + tracked 9th (val+id). strict > => lower-id wins ties.
#define GINS(cc, ee) do {                                                \
    float _c=(cc); int _e=(ee);                                          \
    bool _en = _c > g_v7;                                                \
    bool _md = (!_en) & (_c > g_v8);                                     \
    g_v8 = _en ? g_v7 : (_md ? _c : g_v8);                               \
    g_e8 = _en ? g_e7 : (_md ? _e : g_e8);                               \
    if (_en) {                                                           \
        bool _b0=_c>g_v0,_b1=_c>g_v1,_b2=_c>g_v2,_b3=_c>g_v3,            \
             _b4=_c>g_v4,_b5=_c>g_v5,_b6=_c>g_v6;                        \
        g_v7=_b6?g_v6:_c;            g_e7=_b6?g_e6:_e;                   \
        g_v6=_b5?g_v5:(_b6?_c:g_v6); g_e6=_b5?g_e5:(_b6?_e:g_e6);        \
        g_v5=_b4?g_v4:(_b5?_c:g_v5); g_e5=_b4?g_e4:(_b5?_e:g_e5);        \
        g_v4=_b3?g_v3:(_b4?_c:g_v4); g_e4=_b3?g_e3:(_b4?_e:g_e4);        \
        g_v3=_b2?g_v2:(_b3?_c:g_v3); g_e3=_b2?g_e2:(_b3?_e:g_e3);        \
        g_v2=_b1?g_v1:(_b2?_c:g_v2); g_e2=_b1?g_e1:(_b2?_e:g_e2);        \
        g_v1=_b0?g_v0:(_b1?_c:g_v1); g_e1=_b0?g_e0:(_b1?_e:g_e1);        \
        g_v0=_b0?_c:g_v0;            g_e0=_b0?_e:g_e0;                   \
    } } while (0)

// 9-deep merge list (val+id), gated sorted insert
#define MINS(cc, ee) do {                                                \
    float _c=(cc); int _e=(ee);                                          \
    if (_c > m8) {                                                       \
        bool _b0=_c>m0,_b1=_c>m1,_b2=_c>m2,_b3=_c>m3,_b4=_c>m4,          \
             _b5=_c>m5,_b6=_c>m6,_b7=_c>m7;                              \
        m8=_b7?m7:_c;           n8=_b7?n7:_e;                            \
        m7=_b6?m6:(_b7?_c:m7);  n7=_b6?n6:(_b7?_e:n7);                   \
        m6=_b5?m5:(_b6?_c:m6);  n6=_b5?n5:(_b6?_e:n6);                   \
        m5=_b4?m4:(_b5?_c:m5);  n5=_b4?n4:(_b5?_e:n5);                   \
        m4=_b3?m3:(_b4?_c:m4);  n4=_b3?n3:(_b4?_e:n4);                   \
        m3=_b2?m2:(_b3?_c:m3);  n3=_b2?n2:(_b3?_e:n3);                   \
        m2=_b1?m1:(_b2?_c:m2);  n2=_b1?n1:(_b2?_e:n2);                   \
        m1=_b0?m0:(_b1?_c:m1);  n1=_b0?n0:(_b1?_e:n1);                   \
        m0=_b0?_c:m0;           n0=_b0?_e:n0;                            \
    } } while (0)

// f64 8-deep sorted insert (slow path)
#define DINS(cc, ee) do {                                                \
    double _d=(cc); int _e=(ee);                                         \
    if (_d > s7) {                                                       \
        bool _b0=_d>s0,_b1=_d>s1,_b2=_d>s2,_b3=_d>s3,_b4=_d>s4,          \
             _b5=_d>s5,_b6=_d>s6;                                        \
        s7=_b6?s6:_d;           c7=_b6?c6:_e;                            \
        s6=_b5?s5:(_b6?_d:s6);  c6=_b5?c5:(_b6?_e:c6);                   \
        s5=_b4?s4:(_b5?_d:s5);  c5=_b4?c4:(_b5?_e:c5);                   \
        s4=_b3?s3:(_b4?_d:s4);  c4=_b3?c3:(_b4?_e:c4);                   \
        s3=_b2?s2:(_b3?_d:s3);  c3=_b2?c2:(_b3?_e:c3);                   \
        s2=_b1?s1:(_b2?_d:s2);  c2=_b1?c1:(_b2?_e:c2);                   \
        s1=_b0?s0:(_b1?_d:s1);  c1=_b0?c0:(_b1?_e:c1);                   \
        s0=_b0?_d:s0;           c0=_b0?_e:c0;                            \
    } } while (0)

__global__ __launch_bounds__(THREADS, 4)
void noauxtc_router_kernel(const float* __restrict__ logits,
                           const float* __restrict__ bias,
                           float* __restrict__ out,   // [T*8] weights, [T*8] ids-as-f32
                           int T)
{
    __shared__ float4 tile4[2 * TPB * 8];              // 16 KiB: [half][token][8], xor-swizzled
    __shared__ __align__(16) float bias_sh[NEXP];      // 1 KiB

    const int tid = threadIdx.x;
    const int p   = tid >> 1;          // token-in-block
    const int h   = tid & 1;           // half: owns groups h*4 .. h*4+3
    const int tok0  = blockIdx.x * TPB;
    const int token = tok0 + p;
    const float4* lg4   = (const float4*)logits;
    const float4* bias4 = (const float4*)bias_sh;

    for (int i = tid; i < NEXP; i += THREADS) bias_sh[i] = bias[i];
    // (covered by round-0's post-staging barrier)

    float lv[4][8]; int le[4][8]; float lr[4]; int lre[4];  // per-group top-8 + 9th

    // prefetch round 0: 1024 float4/block, 8/thread, coalesced 128B runs
    float4 pf[8];
    #pragma unroll
    for (int j = 0; j < 8; ++j) {
        int flat = j * THREADS + tid;
        int hh = flat >> 9, rem = flat & 511, pp = rem >> 3, qq = rem & 7;
        pf[j] = lg4[(size_t)(tok0 + pp) * 64 + (hh * 4) * 8 + qq];
    }

    #pragma unroll
    for (int r = 0; r < 4; ++r) {
        __syncthreads();                       // tile free (r=0: also bias_sh ready below)
        #pragma unroll
        for (int j = 0; j < 8; ++j) {
            int flat = j * THREADS + tid;
            int hh = flat >> 9, rem = flat & 511, pp = rem >> 3, qq = rem & 7;
            tile4[hh * 512 + pp * 8 + (qq ^ (pp & 7))] = pf[j];
        }
        __syncthreads();                       // tile ready
        if (r < 3) {                           // prefetch r+1 overlaps compute of r
            #pragma unroll
            for (int j = 0; j < 8; ++j) {
                int flat = j * THREADS + tid;
                int hh = flat >> 9, rem = flat & 511, pp = rem >> 3, qq = rem & 7;
                pf[j] = lg4[(size_t)(tok0 + pp) * 64 + ((r + 1) + hh * 4) * 8 + qq];
            }
        }
        const int g = h * 4 + r;
        float g_v0=-3e38f,g_v1=-3e38f,g_v2=-3e38f,g_v3=-3e38f,g_v4=-3e38f,
              g_v5=-3e38f,g_v6=-3e38f,g_v7=-3e38f,g_v8=-3e38f;
        int g_e0=0,g_e1=0,g_e2=0,g_e3=0,g_e4=0,g_e5=0,g_e6=0,g_e7=0,g_e8=0;
        #pragma unroll 4
        for (int q = 0; q < 8; ++q) {
            float4 x  = tile4[h * 512 + p * 8 + (q ^ (p & 7))];
            float4 bb = bias4[g * 8 + q];      // 2 addrs/wave -> LDS broadcast
            int eb = g * 32 + q * 4;
            float c;
            c = fsigmoid(x.x) + bb.x; GINS(c, eb + 0);
            c = fsigmoid(x.y) + bb.y; GINS(c, eb + 1);
            c = fsigmoid(x.z) + bb.z; GINS(c, eb + 2);
            c = fsigmoid(x.w) + bb.w; GINS(c, eb + 3);
        }
        lv[r][0]=g_v0; lv[r][1]=g_v1; lv[r][2]=g_v2; lv[r][3]=g_v3;
        lv[r][4]=g_v4; lv[r][5]=g_v5; lv[r][6]=g_v6; lv[r][7]=g_v7;
        le[r][0]=g_e0; le[r][1]=g_e1; le[r][2]=g_e2; le[r][3]=g_e3;
        le[r][4]=g_e4; le[r][5]=g_e5; le[r][6]=g_e6; le[r][7]=g_e7;
        lr[r]=g_v8; lre[r]=g_e8;
    }

    // ---------------- group scores: exchange with partner lane ----------------
    float gsA[8];
    #pragma unroll
    for (int r = 0; r < 4; ++r) {
        float own = lv[r][0] + lv[r][1];       // top-2 sum comes free from sorted list
        float oth = __shfl_xor(own, 1, 64);
        gsA[r]     = h ? oth : own;
        gsA[r + 4] = h ? own : oth;
    }

    // ---------------- top-4 groups (rank count, lower idx wins) + margin ----------------
    int selmask = 0; float val4 = 0.f, val5 = 0.f;
    #pragma unroll
    for (int a = 0; a < 8; ++a) {
        int rk = 0;
        #pragma unroll
        for (int b = 0; b < 8; ++b) {
            if (b == a) continue;
            bool beat = (b < a) ? (gsA[b] >= gsA[a]) : (gsA[b] > gsA[a]);
            rk += beat ? 1 : 0;
        }
        selmask |= (rk < 4) ? (1 << a) : 0;
        val4 = (rk == 3) ? gsA[a] : val4;
        val5 = (rk == 4) ? gsA[a] : val5;
    }

    // flagA: ambiguous 4th vs 5th group -> f64 recompute of boundary band (rare)
    if (__builtin_expect(val4 - val5 < EPS_G, 0)) {
        double gd[8];
        #pragma unroll
        for (int a = 0; a < 8; ++a) {
            float gf = gsA[a];
            if (gf >= val5 - EPS_G && gf <= val4 + EPS_G) {
                double a1 = -1e300, a2 = -1e300;
                const float* rowp = logits + (size_t)token * 256 + a * 32;
                for (int k = 0; k < 32; ++k) {
                    double c = dsigmoid(rowp[k]) + (double)bias_sh[a * 32 + k];
                    a2 = fmax(a2, fmin(a1, c)); a1 = fmax(a1, c);
                }
                gd[a] = a1 + a2;
            } else gd[a] = (double)gf;
        }
        int sm = 0;
        #pragma unroll
        for (int a = 0; a < 8; ++a) {
            int rk = 0;
            #pragma unroll
            for (int b = 0; b < 8; ++b) {
                if (b == a) continue;
                bool beat = (b < a) ? (gd[b] >= gd[a]) : (gd[b] > gd[a]);
                rk += beat ? 1 : 0;
            }
            sm |= (rk < 4) ? (1 << a) : 0;
        }
        selmask = sm;
    }

    // ---------------- merge own selected groups into 9-deep list ----------------
    float m0=-3e38f,m1=-3e38f,m2=-3e38f,m3=-3e38f,m4=-3e38f,
          m5=-3e38f,m6=-3e38f,m7=-3e38f,m8=-3e38f;
    int n0=0,n1=0,n2=0,n3=0,n4=0,n5=0,n6=0,n7=0,n8=0;
    #pragma unroll
    for (int r = 0; r < 4; ++r) {
        if ((selmask >> (h * 4 + r)) & 1) {
            MINS(lv[r][0], le[r][0]); MINS(lv[r][1], le[r][1]);
            MINS(lv[r][2], le[r][2]); MINS(lv[r][3], le[r][3]);
            MINS(lv[r][4], le[r][4]); MINS(lv[r][5], le[r][5]);
            MINS(lv[r][6], le[r][6]); MINS(lv[r][7], le[r][7]);
            MINS(lr[r], lre[r]);
        }
    }

    // ---------------- exchange partner's 9 and merge ----------------
    float pm0=__shfl_xor(m0,1,64), pm1=__shfl_xor(m1,1,64), pm2=__shfl_xor(m2,1,64),
          pm3=__shfl_xor(m3,1,64), pm4=__shfl_xor(m4,1,64), pm5=__shfl_xor(m5,1,64),
          pm6=__shfl_xor(m6,1,64), pm7=__shfl_xor(m7,1,64), pm8=__shfl_xor(m8,1,64);
    int   pn0=__shfl_xor(n0,1,64), pn1=__shfl_xor(n1,1,64), pn2=__shfl_xor(n2,1,64),
          pn3=__shfl_xor(n3,1,64), pn4=__shfl_xor(n4,1,64), pn5=__shfl_xor(n5,1,64),
          pn6=__shfl_xor(n6,1,64), pn7=__shfl_xor(n7,1,64), pn8=__shfl_xor(n8,1,64);
    // even lanes: own ids < partner ids -> strict > keeps lower id first on ties
    MINS(pm0, pn0); MINS(pm1, pn1); MINS(pm2, pn2); MINS(pm3, pn3);
    MINS(pm4, pn4); MINS(pm5, pn5); MINS(pm6, pn6); MINS(pm7, pn7); MINS(pm8, pn8);

    // ---------------- fast-path result + flagB ----------------
    float w0 = m0 - bias_sh[n0], w1 = m1 - bias_sh[n1], w2 = m2 - bias_sh[n2],
          w3 = m3 - bias_sh[n3], w4 = m4 - bias_sh[n4], w5 = m5 - bias_sh[n5],
          w6 = m6 - bias_sh[n6], w7 = m7 - bias_sh[n7];
    int o0=n0,o1=n1,o2=n2,o3=n3,o4=n4,o5=n5,o6=n6,o7=n7;

    bool flagB = ((m0-m1)<EPS_S)|((m1-m2)<EPS_S)|((m2-m3)<EPS_S)|((m3-m4)<EPS_S)|
                 ((m4-m5)<EPS_S)|((m5-m6)<EPS_S)|((m6-m7)<EPS_S)|((m7-m8)<EPS_S);
    if (__builtin_expect(flagB, 0)) {
        // f64 re-resolve of the merged top-9 candidates (true top-8 is within them)
        double s0=-1e300,s1=-1e300,s2=-1e300,s3=-1e300,s4=-1e300,
               s5=-1e300,s6=-1e300,s7=-1e300;
        int c0=0,c1=0,c2=0,c3=0,c4=0,c5=0,c6=0,c7=0;
        const float* row = logits + (size_t)token * 256;
        int ci0=n0,ci1=n1,ci2=n2,ci3=n3,ci4=n4,ci5=n5,ci6=n6,ci7=n7,ci8=n8;
        double cs;
        cs = dsigmoid(row[ci0]) + (double)bias_sh[ci0]; DINS(cs, ci0);
        cs = dsigmoid(row[ci1]) + (double)bias_sh[ci1]; DINS(cs, ci1);
        cs = dsigmoid(row[ci2]) + (double)bias_sh[ci2]; DINS(cs, ci2);
        cs = dsigmoid(row[ci3]) + (double)bias_sh[ci3]; DINS(cs, ci3);
        cs = dsigmoid(row[ci4]) + (double)bias_sh[ci4]; DINS(cs, ci4);
        cs = dsigmoid(row[ci5]) + (double)bias_sh[ci5]; DINS(cs, ci5);
        cs = dsigmoid(row[ci6]) + (double)bias_sh[ci6]; DINS(cs, ci6);
        cs = dsigmoid(row[ci7]) + (double)bias_sh[ci7]; DINS(cs, ci7);
        cs = dsigmoid(row[ci8]) + (double)bias_sh[ci8]; DINS(cs, ci8);
        w0=(float)(s0-(double)bias_sh[c0]); o0=c0;
        w1=(float)(s1-(double)bias_sh[c1]); o1=c1;
        w2=(float)(s2-(double)bias_sh[c2]); o2=c2;
        w3=(float)(s3-(double)bias_sh[c3]); o3=c3;
        w4=(float)(s4-(double)bias_sh[c4]); o4=c4;
        w5=(float)(s5-(double)bias_sh[c5]); o5=c5;
        w6=(float)(s6-(double)bias_sh[c6]); o6=c6;
        w7=(float)(s7-(double)bias_sh[c7]); o7=c7;
    }

    // ---------------- epilogue (even lanes own the token) ----------------
    if (h == 0) {
        float sum = ((w0+w1)+(w2+w3)) + ((w4+w5)+(w6+w7));
        float scl = 2.5f / (sum + 1e-20f);
        float4 oa, ob;
        oa.x=w0*scl; oa.y=w1*scl; oa.z=w2*scl; oa.w=w3*scl;
        ob.x=w4*scl; ob.y=w5*scl; ob.z=w6*scl; ob.w=w7*scl;
        *(float4*)(out + (size_t)token*8)     = oa;
        *(float4*)(out + (size_t)token*8 + 4) = ob;
        float* oid = out + (size_t)T*8;
        float4 ia, ib;
        ia.x=(float)o0; ia.y=(float)o1; ia.z=(float)o2; ia.w=(float)o3;
        ib.x=(float)o4; ib.y=(float)o5; ib.z=(float)o6; ib.w=(float)o7;
        *(float4*)(oid + (size_t)token*8)     = ia;
        *(float4*)(oid + (size_t)token*8 + 4) = ib;
    }
}

extern "C" void kernel_launch(void* const* d_in, const int* in_sizes, int n_in,
                              void* d_out, int out_size, void* d_ws, size_t ws_size,
                              hipStream_t stream) {
    const float* logits = (const float*)d_in[0];
    const float* bias   = (const float*)d_in[1];
    float* out = (float*)d_out;
    int T = in_sizes[0] / NEXP;        // 131072
    int nblocks = T / TPB;             // 2048
    noauxtc_router_kernel<<<nblocks, THREADS, 0, stream>>>(logits, bias, out, T);
}